// Round 3
// baseline (144.240 us; speedup 1.0000x reference)
//
#include <hip/hip_runtime.h>

// Problem: T=4096, C=64, D=512.
// out[t,c,d] = exp(rowsum(W)[c] * colsum(W)[d]) / D   (independent of t and x)

#define T_DIM 4096
#define C_DIM 64
#define D_DIM 512

typedef float f32x4 __attribute__((ext_vector_type(4)));

// One block, 512 threads: compute row sums (C), column sums (D), then the
// (C x D) remap tile into workspace.
__global__ void compute_remap_kernel(const float* __restrict__ w,
                                     float* __restrict__ remap) {
    __shared__ float rs[C_DIM];
    __shared__ float cs[D_DIM];
    const int tid = threadIdx.x;  // 0..511

    // Column sum for column `tid`: sum over 64 rows (wave-coalesced loads).
    {
        float c0 = 0.0f, c1 = 0.0f, c2 = 0.0f, c3 = 0.0f;
        #pragma unroll
        for (int c = 0; c < C_DIM; c += 4) {
            c0 += w[(c + 0) * D_DIM + tid];
            c1 += w[(c + 1) * D_DIM + tid];
            c2 += w[(c + 2) * D_DIM + tid];
            c3 += w[(c + 3) * D_DIM + tid];
        }
        cs[tid] = (c0 + c1) + (c2 + c3);
    }

    // Row sums: threads 0..63 each own one row; float4 loads, 4 accumulators
    // to break the dependent-add chain.
    if (tid < C_DIM) {
        const f32x4* wrow = (const f32x4*)(w + tid * D_DIM);  // 128 float4s
        float a0 = 0.0f, a1 = 0.0f, a2 = 0.0f, a3 = 0.0f;
        #pragma unroll
        for (int i = 0; i < 128; i += 4) {
            f32x4 q0 = wrow[i + 0];
            f32x4 q1 = wrow[i + 1];
            f32x4 q2 = wrow[i + 2];
            f32x4 q3 = wrow[i + 3];
            a0 += (q0.x + q0.y) + (q0.z + q0.w);
            a1 += (q1.x + q1.y) + (q1.z + q1.w);
            a2 += (q2.x + q2.y) + (q2.z + q2.w);
            a3 += (q3.x + q3.y) + (q3.z + q3.w);
        }
        rs[tid] = (a0 + a1) + (a2 + a3);
    }
    __syncthreads();

    const float inv_det = 1.0f / (float)D_DIM;  // det_i = D for zero colsums
    for (int idx = tid; idx < C_DIM * D_DIM; idx += 512) {
        const int c = idx >> 9;           // / D_DIM
        const int d = idx & (D_DIM - 1);  // % D_DIM
        remap[idx] = expf(rs[c] * cs[d]) * inv_det;
    }
}

// Broadcast the 32768-float (8192 x float4) tile to all T slices.
// 2048 blocks x 256 threads = 524288 threads: grid stride (524288 float4s) is
// a multiple of the tile size (8192 float4s), so each thread's source value is
// loop-invariant -> load once, then 64 non-temporal streaming stores.
__global__ void broadcast_remap_kernel(const f32x4* __restrict__ remap,
                                       f32x4* __restrict__ out) {
    const unsigned tid = blockIdx.x * blockDim.x + threadIdx.x;
    const unsigned SRC4 = (C_DIM * D_DIM) / 4;  // 8192
    const f32x4 v = remap[tid & (SRC4 - 1)];

    const size_t total = (size_t)T_DIM * C_DIM * D_DIM / 4;  // 33554432
    const size_t stride = (size_t)gridDim.x * blockDim.x;    // 524288
    for (size_t g = tid; g < total; g += stride) {
        __builtin_nontemporal_store(v, &out[g]);
    }
}

extern "C" void kernel_launch(void* const* d_in, const int* in_sizes, int n_in,
                              void* d_out, int out_size, void* d_ws, size_t ws_size,
                              hipStream_t stream) {
    // d_in[0] = x (4096 x 512, unused by the math), d_in[1] = weight (64 x 512)
    const float* weight = (const float*)d_in[1];
    float* remap = (float*)d_ws;   // 32768 floats = 128 KiB scratch
    float* out = (float*)d_out;

    compute_remap_kernel<<<1, 512, 0, stream>>>(weight, remap);
    broadcast_remap_kernel<<<2048, 256, 0, stream>>>((const f32x4*)remap,
                                                     (f32x4*)out);
}

// Round 4
// 129.093 us; speedup vs baseline: 1.1173x; 1.1173x over previous
//
#include <hip/hip_runtime.h>

// Problem: T=4096, C=64, D=512.
// out[t,c,d] = exp(rowsum(W)[c] * colsum(W)[d]) / D   (independent of t and x)
//
// Fully fused single kernel: each block computes exactly the remap values it
// will store (2 row-sums + 4 col-sums per thread, read straight from W, which
// is 128 KiB and L2-resident), then streams 64 NT float4 stores per thread.
//
// Geometry: 2048 blocks x 256 threads = 524288 threads = 524288 float4s per
// sweep; total 33554432 float4s -> exactly 64 iterations; the source value is
// loop-invariant per thread.

#define T_DIM 4096
#define C_DIM 64
#define D_DIM 512

typedef float f32x4 __attribute__((ext_vector_type(4)));

__global__ __launch_bounds__(256) void fused_broadcast_kernel(
    const float* __restrict__ w, f32x4* __restrict__ out) {
    const int t = threadIdx.x;              // 0..255
    const unsigned b = blockIdx.x;          // 0..2047
    const unsigned tid = b * 256u + t;

    // ---- which remap entries does this thread store? ----
    // float4 slice index j4 = tid & 8191; slice-local float idx s = 4*j4+k.
    // c = s>>9 is uniform across k: c = (b&31)*2 + (t>>7).
    // d = (4t+k) & 511 = dbase + k, dbase = (4t)&511  (independent of b).
    const int c0 = (int)(b & 31u) * 2;      // block's two rows
    const int c1 = c0 + 1;
    const int dbase = (4 * t) & (D_DIM - 1);

    // ---- row sums rs[c0], rs[c1]: block reduce over 512 floats each ----
    float p0 = w[c0 * D_DIM + t] + w[c0 * D_DIM + 256 + t];
    float p1 = w[c1 * D_DIM + t] + w[c1 * D_DIM + 256 + t];
    #pragma unroll
    for (int off = 32; off > 0; off >>= 1) {
        p0 += __shfl_down(p0, off);
        p1 += __shfl_down(p1, off);
    }
    __shared__ float red[8];                // 4 waves x 2 rows
    const int wave = t >> 6, lane = t & 63;
    if (lane == 0) { red[wave * 2] = p0; red[wave * 2 + 1] = p1; }
    __syncthreads();
    const float rs0 = (red[0] + red[2]) + (red[4] + red[6]);
    const float rs1 = (red[1] + red[3]) + (red[5] + red[7]);
    const float rs = (t >> 7) ? rs1 : rs0;

    // ---- col sums cs[dbase..dbase+3]: 64 coalesced f32x4 loads ----
    const f32x4* col = (const f32x4*)(w + dbase);   // row stride = 128 f32x4
    f32x4 a0 = {0.f, 0.f, 0.f, 0.f}, a1 = a0, a2 = a0, a3 = a0;
    #pragma unroll
    for (int r = 0; r < C_DIM; r += 4) {
        a0 += col[(r + 0) * (D_DIM / 4)];
        a1 += col[(r + 1) * (D_DIM / 4)];
        a2 += col[(r + 2) * (D_DIM / 4)];
        a3 += col[(r + 3) * (D_DIM / 4)];
    }
    const f32x4 cs4 = (a0 + a1) + (a2 + a3);

    // ---- remap value (det = D for zero input colsums) ----
    const float inv_det = 1.0f / (float)D_DIM;
    f32x4 v;
    v.x = expf(rs * cs4.x) * inv_det;
    v.y = expf(rs * cs4.y) * inv_det;
    v.z = expf(rs * cs4.z) * inv_det;
    v.w = expf(rs * cs4.w) * inv_det;

    // ---- stream 64 NT stores, grid-stride ----
    const size_t total = (size_t)T_DIM * C_DIM * D_DIM / 4;  // 33554432
    const size_t stride = 2048u * 256u;                      // 524288
    for (size_t g = tid; g < total; g += stride) {
        __builtin_nontemporal_store(v, &out[g]);
    }
}

extern "C" void kernel_launch(void* const* d_in, const int* in_sizes, int n_in,
                              void* d_out, int out_size, void* d_ws, size_t ws_size,
                              hipStream_t stream) {
    // d_in[0] = x (unused by the math), d_in[1] = weight (64 x 512 f32)
    const float* weight = (const float*)d_in[1];
    fused_broadcast_kernel<<<2048, 256, 0, stream>>>(weight, (f32x4*)d_out);
}

// Round 5
// 97.107 us; speedup vs baseline: 1.4854x; 1.3294x over previous
//
#include <hip/hip_runtime.h>

// Problem: T=4096, C=64, D=512.
// out[t,c,d] = exp(rowsum(W)[c] * colsum(W)[d]) / D   (independent of t and x)
//
// Fused single kernel, LOW-occupancy config mirroring rocclr fillBuffer
// (which sustains 6.6+ TB/s of pure writes at ~10% occupancy): 256 blocks x
// 256 threads = 1 block/CU, each thread streams 512 NT float4 stores at 1 MB
// grid stride. Stride (65536 float4) is a multiple of the remap tile (8192
// float4), so each thread's source value is loop-invariant.

#define T_DIM 4096
#define C_DIM 64
#define D_DIM 512

typedef float f32x4 __attribute__((ext_vector_type(4)));

__global__ __launch_bounds__(256) void fused_broadcast_kernel(
    const float* __restrict__ w, f32x4* __restrict__ out) {
    const int t = threadIdx.x;              // 0..255
    const unsigned b = blockIdx.x;          // 0..255
    const unsigned tid = b * 256u + t;      // 0..65535

    // ---- which remap entries does this thread store? ----
    // source float4 index = tid & 8191; c = (tid>>7) & 63 uniform per 128
    // threads; d-group dbase = (4t) & 511 (independent of b).
    const int c0 = (int)((b & 31u) * 2u);   // rows covered by this block
    const int c1 = c0 + 1;
    const int dbase = (4 * t) & (D_DIM - 1);

    // ---- row sums rs[c0], rs[c1]: block reduce over 512 floats each ----
    float p0 = w[c0 * D_DIM + t] + w[c0 * D_DIM + 256 + t];
    float p1 = w[c1 * D_DIM + t] + w[c1 * D_DIM + 256 + t];
    #pragma unroll
    for (int off = 32; off > 0; off >>= 1) {
        p0 += __shfl_down(p0, off);
        p1 += __shfl_down(p1, off);
    }
    __shared__ float red[8];                // 4 waves x 2 rows
    const int wave = t >> 6, lane = t & 63;
    if (lane == 0) { red[wave * 2] = p0; red[wave * 2 + 1] = p1; }
    __syncthreads();
    const float rs0 = (red[0] + red[2]) + (red[4] + red[6]);
    const float rs1 = (red[1] + red[3]) + (red[5] + red[7]);
    const float rs = (t >> 7) ? rs1 : rs0;

    // ---- col sums cs[dbase..dbase+3]: 64 coalesced f32x4 loads (L2-hot) ----
    const f32x4* col = (const f32x4*)(w + dbase);   // row stride = 128 f32x4
    f32x4 a0 = {0.f, 0.f, 0.f, 0.f}, a1 = a0, a2 = a0, a3 = a0;
    #pragma unroll
    for (int r = 0; r < C_DIM; r += 4) {
        a0 += col[(r + 0) * (D_DIM / 4)];
        a1 += col[(r + 1) * (D_DIM / 4)];
        a2 += col[(r + 2) * (D_DIM / 4)];
        a3 += col[(r + 3) * (D_DIM / 4)];
    }
    const f32x4 cs4 = (a0 + a1) + (a2 + a3);

    // ---- remap value (det = D for zero input colsums) ----
    const float inv_det = 1.0f / (float)D_DIM;
    f32x4 v;
    v.x = expf(rs * cs4.x) * inv_det;
    v.y = expf(rs * cs4.y) * inv_det;
    v.z = expf(rs * cs4.z) * inv_det;
    v.w = expf(rs * cs4.w) * inv_det;

    // ---- stream 512 NT stores, 1 MB grid stride ----
    const unsigned STRIDE = 256u * 256u;     // 65536 float4 = multiple of 8192
    const int ITERS = (T_DIM * C_DIM * D_DIM / 4) / STRIDE;  // 512
    f32x4* p = out + tid;
    #pragma unroll 4
    for (int i = 0; i < ITERS; ++i) {
        __builtin_nontemporal_store(v, p);
        p += STRIDE;
    }
}

extern "C" void kernel_launch(void* const* d_in, const int* in_sizes, int n_in,
                              void* d_out, int out_size, void* d_ws, size_t ws_size,
                              hipStream_t stream) {
    // d_in[0] = x (unused by the math), d_in[1] = weight (64 x 512 f32)
    const float* weight = (const float*)d_in[1];
    fused_broadcast_kernel<<<256, 256, 0, stream>>>(weight, (f32x4*)d_out);
}